// Round 7
// baseline (211.261 us; speedup 1.0000x reference)
//
#include <hip/hip_runtime.h>

typedef short v8s __attribute__((ext_vector_type(8)));
typedef float v4f __attribute__((ext_vector_type(4)));
typedef unsigned int v2u __attribute__((ext_vector_type(2)));
typedef unsigned int v4u __attribute__((ext_vector_type(4)));
typedef unsigned short ushort_t;

#define NC 256
#define ND 128
#define ROW_B 528              // LDS row stride: 512B data + 16B pad (bank spread)

__device__ __forceinline__ unsigned short f2bf(float f) {
  union { float f; unsigned int u; } v; v.f = f;
  unsigned int u = v.u;
  unsigned int r = (u + 0x7fffu + ((u >> 16) & 1u)) >> 16;
  return (unsigned short)r;
}

__device__ __forceinline__ unsigned int cvt_pk_bf16(float a, float b) {
  unsigned int r;
  asm("v_cvt_pk_bf16_f32 %0, %1, %2" : "=v"(r) : "v"(a), "v"(b));
  return r;
}

__device__ __forceinline__ float bf_lo(unsigned int u) { return __uint_as_float(u << 16); }
__device__ __forceinline__ float bf_hi(unsigned int u) { return __uint_as_float(u & 0xffff0000u); }

// ---------------- prep: 16x16x32-fragment-arranged bf16 P/G/PT, norms, gate ----------
// dist A-frag (A = P tile 16c x 32k): addr ((ct*4+s)*64 + lane)*8 + j
//   holds P[ct*16 + (lane&15)][s*32 + (lane>>4)*8 + j]
// blend A-frag (A = P^T tile 16d x 32c): addr ((dt*8+s2)*64 + lane)*8 + j
//   holds P[s2*32 + (lane>>4)*8 + j][dt*16 + (lane&15)]
__global__ void som_prep_kernel(const float* __restrict__ P, const float* __restrict__ G,
                                const float* __restrict__ gate_logits,
                                ushort_t* __restrict__ PbfA, ushort_t* __restrict__ GbfA,
                                ushort_t* __restrict__ PTbfA,
                                float* __restrict__ b2p, float* __restrict__ b2g,
                                float* __restrict__ gatev) {
  int c = blockIdx.x;      // 0..255
  int t = threadIdx.x;     // 0..127 (= d / k index)
  float p = P[c * ND + t];
  float g = G[c * ND + t];

  {  // dist fragments: row c, k = t
    int ct = c >> 4, l15 = c & 15;
    int s = t >> 5, q4 = (t >> 3) & 3, j = t & 7;
    int lane = l15 + 16 * q4;
    int idx = ((ct * 4 + s) * 64 + lane) * 8 + j;
    PbfA[idx] = f2bf(p);
    GbfA[idx] = f2bf(g);
  }
  {  // blend fragments: row d = t, k = c
    int dt = t >> 4, l15 = t & 15;
    int s2 = c >> 5, q4 = (c >> 3) & 3, j = c & 7;
    int lane = l15 + 16 * q4;
    PTbfA[((dt * 8 + s2) * 64 + lane) * 8 + j] = f2bf(p);
  }

  float pp = p * p, gg = g * g;
  #pragma unroll
  for (int m = 1; m < 64; m <<= 1) { pp += __shfl_xor(pp, m); gg += __shfl_xor(gg, m); }
  __shared__ float sp[2], sg[2];
  if ((t & 63) == 0) { sp[t >> 6] = pp; sg[t >> 6] = gg; }
  __syncthreads();
  if (t == 0) {
    b2p[c] = sp[0] + sp[1];
    b2g[c] = sg[0] + sg[1];
    gatev[c] = 1.f / (1.f + expf(-gate_logits[c]));
  }
}

// ---------------- fused main kernel (16 rows/wave, 16x16x32 MFMA) ----------------
// S^T = P(16c x 32k) * X^T(32k x 16m): C/D col = m = lane&15, row c = ct*16+(lane>>4)*4+r.
// u (bf16, gated, unscaled) -> per-wave 8448B padded LDS tile [16 m][256 c (+8 pad)].
// w / blended emitted via LDS transpose as full-128B-line stores.
__global__ __launch_bounds__(256, 4) void som_main_kernel(
    const float* __restrict__ x,
    const ushort_t* __restrict__ PbfA,
    const ushort_t* __restrict__ GbfA,
    const ushort_t* __restrict__ PTbfA,
    const float* __restrict__ b2p,
    const float* __restrict__ b2g,
    const float* __restrict__ gatev,
    const float* __restrict__ temp_raw,
    float* __restrict__ blended_out,
    float* __restrict__ w_out)
{
  __shared__ char smem[4 * 16 * ROW_B];        // 33792 B, per-wave private 8448B
  const int tid  = threadIdx.x;
  const int wid  = tid >> 6;
  const int lane = tid & 63;
  const int l15  = lane & 15;
  const int q4   = lane >> 4;                  // 0..3
  const long long R = ((long long)blockIdx.x * 4 + wid) * 16;
  char* wl = smem + wid * 16 * ROW_B;

  float traw = temp_raw[0];
  float sgm = 1.f / (1.f + __builtin_amdgcn_exp2f(-traw * 1.44269504f));
  float T = sgm * (1.f - 1e-3f) + 1e-3f;
  float k2 = 1.44269504f / T;                  // e = exp2(-d * k2)

  // ---- X B-fragments (col m=l15, k = s*32 + q4*8 + j) + exact f32 row norm ----
  const float* xr = x + (R + l15) * ND + q4 * 8;
  v8s xb[4];
  float a2 = 0.f;
  #pragma unroll
  for (int s = 0; s < 4; ++s) {
    v4f lo = *(const v4f*)(xr + s * 32);
    v4f h4 = *(const v4f*)(xr + s * 32 + 4);
    v4u w;
    w[0] = cvt_pk_bf16(lo[0], lo[1]);
    w[1] = cvt_pk_bf16(lo[2], lo[3]);
    w[2] = cvt_pk_bf16(h4[0], h4[1]);
    w[3] = cvt_pk_bf16(h4[2], h4[3]);
    xb[s] = __builtin_bit_cast(v8s, w);
    #pragma unroll
    for (int j = 0; j < 4; ++j) {
      a2 = fmaf(lo[j], lo[j], a2);
      a2 = fmaf(h4[j], h4[j], a2);
    }
  }
  a2 += __shfl_xor(a2, 16);
  a2 += __shfl_xor(a2, 32);                    // ||x_row||^2 for row l15, in all 4 lanes

  // ---- dist loop: MFMA -> e*gate -> bf16 -> LDS (nothing retained) ----
  float s1 = 0.f, su = 0.f;
  const ushort_t* pb = PbfA + lane * 8;
  const ushort_t* gb = GbfA + lane * 8;
  #pragma unroll
  for (int ct = 0; ct < 16; ++ct) {
    v4f aP = {0.f,0.f,0.f,0.f}, aG = {0.f,0.f,0.f,0.f};
    #pragma unroll
    for (int s = 0; s < 4; ++s) {
      v8s ap = *(const v8s*)(pb + (ct * 4 + s) * 512);
      v8s ag = *(const v8s*)(gb + (ct * 4 + s) * 512);
      aP = __builtin_amdgcn_mfma_f32_16x16x32_bf16(ap, xb[s], aP, 0, 0, 0);
      aG = __builtin_amdgcn_mfma_f32_16x16x32_bf16(ag, xb[s], aG, 0, 0, 0);
    }
    int c0 = ct * 16 + q4 * 4;
    v4f bp = *(const v4f*)(b2p + c0);
    v4f bg = *(const v4f*)(b2g + c0);
    v4f gt = *(const v4f*)(gatev + c0);
    float uf[4];
    #pragma unroll
    for (int r = 0; r < 4; ++r) {
      float d2a = fmaf(-2.f, aP[r], a2 + bp[r]);
      float d2b = fmaf(-2.f, aG[r], a2 + bg[r]);
      float d = __builtin_amdgcn_sqrtf(fmaxf(d2a, 1e-12f))
              + __builtin_amdgcn_sqrtf(fmaxf(d2b, 1e-12f));
      float e = __builtin_amdgcn_exp2f(-d * k2);
      float uu = e * gt[r];
      s1 += e; su += uu;
      uf[r] = uu;
    }
    v2u pk;
    pk[0] = cvt_pk_bf16(uf[0], uf[1]);
    pk[1] = cvt_pk_bf16(uf[2], uf[3]);
    // u[m=l15][c0..c0+3]: b64 write, padded-row bank spread
    *(v2u*)(wl + l15 * ROW_B + ct * 32 + q4 * 8) = pk;
  }
  s1 += __shfl_xor(s1, 16); s1 += __shfl_xor(s1, 32);
  su += __shfl_xor(su, 16); su += __shfl_xor(su, 32);
  float scale = 1.f / (su + 1e-8f * (s1 + 1e-8f));   // exact algebra of double norm

  // ---- w emit: 16 rows per instr, full 128B lines (2 consecutive 64B stores) ----
  const int erow = lane >> 2;                  // 0..15
  const int ek   = lane & 3;                   // 0..3
  float rsc = __shfl(scale, erow);             // lane 'erow' has l15 == erow
  float* wdst = w_out + (size_t)(R + erow) * NC + ek * 8;
  #pragma unroll
  for (int ch = 0; ch < 8; ++ch) {
    v4u pk = *(const v4u*)(wl + erow * ROW_B + ch * 64 + ek * 16);
    v4f w0, w1;
    w0[0] = bf_lo(pk[0]) * rsc; w0[1] = bf_hi(pk[0]) * rsc;
    w0[2] = bf_lo(pk[1]) * rsc; w0[3] = bf_hi(pk[1]) * rsc;
    w1[0] = bf_lo(pk[2]) * rsc; w1[1] = bf_hi(pk[2]) * rsc;
    w1[2] = bf_lo(pk[3]) * rsc; w1[3] = bf_hi(pk[3]) * rsc;
    *(v4f*)(wdst + ch * 32)     = w0;
    *(v4f*)(wdst + ch * 32 + 4) = w1;
  }

  // ---- blend: blended^T = PT(16d x 32c) * U^T(32c x 16m), B-frags from LDS ----
  v4f acc[8];
  #pragma unroll
  for (int dt = 0; dt < 8; ++dt) acc[dt] = (v4f){0.f,0.f,0.f,0.f};
  const ushort_t* tb = PTbfA + lane * 8;
  #pragma unroll
  for (int s2 = 0; s2 < 8; ++s2) {
    v4u bw = *(const v4u*)(wl + l15 * ROW_B + s2 * 64 + q4 * 16);
    v8s bfrag = __builtin_bit_cast(v8s, bw);
    #pragma unroll
    for (int dt = 0; dt < 8; ++dt) {
      v8s pa = *(const v8s*)(tb + (dt * 8 + s2) * 512);
      acc[dt] = __builtin_amdgcn_mfma_f32_16x16x32_bf16(pa, bfrag, acc[dt], 0, 0, 0);
    }
  }

  // ---- blended: scale, stage f32 tile [16 m][128 d (+4 pad)] in same LDS, emit lines ----
  #pragma unroll
  for (int dt = 0; dt < 8; ++dt) {
    v4f ov;
    ov[0] = acc[dt][0] * scale;
    ov[1] = acc[dt][1] * scale;
    ov[2] = acc[dt][2] * scale;
    ov[3] = acc[dt][3] * scale;   // rows d = dt*16 + q4*4 + (0..3), col m = l15
    *(v4f*)(wl + l15 * ROW_B + dt * 64 + q4 * 16) = ov;
  }
  float* bdst = blended_out + (size_t)(R + erow) * ND + ek * 8;
  #pragma unroll
  for (int ch = 0; ch < 4; ++ch) {
    v4f b0 = *(const v4f*)(wl + erow * ROW_B + ch * 128 + ek * 32);
    v4f b1 = *(const v4f*)(wl + erow * ROW_B + ch * 128 + ek * 32 + 16);
    *(v4f*)(bdst + ch * 32)     = b0;
    *(v4f*)(bdst + ch * 32 + 4) = b1;
  }
}

extern "C" void kernel_launch(void* const* d_in, const int* in_sizes, int n_in,
                              void* d_out, int out_size, void* d_ws, size_t ws_size,
                              hipStream_t stream) {
  const float* x    = (const float*)d_in[0];
  const float* P    = (const float*)d_in[1];
  const float* G    = (const float*)d_in[2];
  const float* traw = (const float*)d_in[3];
  const float* gl   = (const float*)d_in[4];
  const int N = in_sizes[0] / ND;             // 262144

  char* ws = (char*)d_ws;
  ushort_t* PbfA  = (ushort_t*)(ws);
  ushort_t* GbfA  = (ushort_t*)(ws + 65536);
  ushort_t* PTbfA = (ushort_t*)(ws + 131072);
  float* b2p   = (float*)(ws + 196608);
  float* b2g   = (float*)(ws + 197632);
  float* gatev = (float*)(ws + 198656);

  float* blended = (float*)d_out;
  float* wout    = blended + (size_t)N * ND;

  som_prep_kernel<<<NC, ND, 0, stream>>>(P, G, gl, PbfA, GbfA, PTbfA, b2p, b2g, gatev);
  som_main_kernel<<<N / 64, 256, 0, stream>>>(x, PbfA, GbfA, PTbfA, b2p, b2g, gatev,
                                              traw, blended, wout);
}

// Round 8
// 165.320 us; speedup vs baseline: 1.2779x; 1.2779x over previous
//
#include <hip/hip_runtime.h>

typedef short v8s __attribute__((ext_vector_type(8)));
typedef float v4f __attribute__((ext_vector_type(4)));
typedef float f32x16 __attribute__((ext_vector_type(16)));
typedef unsigned int v2u __attribute__((ext_vector_type(2)));
typedef unsigned int v4u __attribute__((ext_vector_type(4)));
typedef unsigned short ushort_t;

#define NC 256
#define ND 128

__device__ __forceinline__ unsigned short f2bf(float f) {
  union { float f; unsigned int u; } v; v.f = f;
  unsigned int u = v.u;
  unsigned int r = (u + 0x7fffu + ((u >> 16) & 1u)) >> 16;
  return (unsigned short)r;
}

__device__ __forceinline__ unsigned int cvt_pk_bf16(float a, float b) {
  unsigned int r;
  asm("v_cvt_pk_bf16_f32 %0, %1, %2" : "=v"(r) : "v"(a), "v"(b));
  return r;
}

__device__ __forceinline__ float bf_lo(unsigned int u) { return __uint_as_float(u << 16); }
__device__ __forceinline__ float bf_hi(unsigned int u) { return __uint_as_float(u & 0xffff0000u); }

// ---------------- prep: 32x32x16-fragment-arranged bf16 P/G/PT, norms, gate (R6) ------
__global__ void som_prep_kernel(const float* __restrict__ P, const float* __restrict__ G,
                                const float* __restrict__ gate_logits,
                                ushort_t* __restrict__ PbfA, ushort_t* __restrict__ GbfA,
                                ushort_t* __restrict__ PTbfA,
                                float* __restrict__ b2p, float* __restrict__ b2g,
                                float* __restrict__ gatev) {
  int c = blockIdx.x;      // 0..255
  int t = threadIdx.x;     // 0..127 (= d / k index)
  float p = P[c * ND + t];
  float g = G[c * ND + t];

  int ct = c >> 5, l31 = c & 31;
  int s = t >> 4, hia = (t >> 3) & 1, j = t & 7;
  int lane = l31 + 32 * hia;
  PbfA[((ct * 8 + s) * 64 + lane) * 8 + j] = f2bf(p);
  GbfA[((ct * 8 + s) * 64 + lane) * 8 + j] = f2bf(g);

  int dt = t >> 5, l31d = t & 31;
  int sc = c >> 4, hic = (c >> 3) & 1, jc = c & 7;
  int laned = l31d + 32 * hic;
  PTbfA[((dt * 16 + sc) * 64 + laned) * 8 + jc] = f2bf(p);

  float pp = p * p, gg = g * g;
  #pragma unroll
  for (int m = 1; m < 64; m <<= 1) { pp += __shfl_xor(pp, m); gg += __shfl_xor(gg, m); }
  __shared__ float sp[2], sg[2];
  if ((t & 63) == 0) { sp[t >> 6] = pp; sg[t >> 6] = gg; }
  __syncthreads();
  if (t == 0) {
    b2p[c] = sp[0] + sp[1];
    b2g[c] = sg[0] + sg[1];
    gatev[c] = 1.f / (1.f + expf(-gate_logits[c]));
  }
}

// ---------------- fused main kernel: wave-pair per 32-row tile ----------------
// Pair p (waves 2p, 2p+1) owns 32 rows. Wave half h: dist ct in [h*4, h*4+4)
// (c-half), blend dt in [h*2, h*2+2) (d-half). Shared 16KB u tile per pair.
__global__ __launch_bounds__(512, 4) void som_main_kernel(
    const float* __restrict__ x,
    const ushort_t* __restrict__ PbfA,
    const ushort_t* __restrict__ GbfA,
    const ushort_t* __restrict__ PTbfA,
    const float* __restrict__ b2p,
    const float* __restrict__ b2g,
    const float* __restrict__ gatev,
    const float* __restrict__ temp_raw,
    float* __restrict__ blended_out,
    float* __restrict__ w_out)
{
  __shared__ char smem[4 * 16384 + 2048];      // 4 pair-tiles + sums (128 f32/pair)
  const int tid  = threadIdx.x;
  const int wid  = tid >> 6;                   // 0..7
  const int pair = wid >> 1;                   // 0..3
  const int h    = wid & 1;                    // c/d half
  const int lane = tid & 63;
  const int l31  = lane & 31;
  const int hi   = lane >> 5;
  const long long R = ((long long)blockIdx.x * 4 + pair) * 32;
  char* wl = smem + pair * 16384;
  float* sums = (float*)(smem + 65536) + pair * 128;   // [h][s1:32][su:32]
  const int rsw = (l31 & 7) << 4;

  float traw = temp_raw[0];
  float sgm = 1.f / (1.f + __builtin_amdgcn_exp2f(-traw * 1.44269504f));
  float T = sgm * (1.f - 1e-3f) + 1e-3f;
  float k2 = 1.44269504f / T;                  // e = exp2(-d * k2)

  // ---- X B-fragments (col m = l31, full k) + exact f32 row norm ----
  const float* xr = x + (R + l31) * ND + hi * 8;
  v8s xb[8];
  float a2 = 0.f;
  #pragma unroll
  for (int s = 0; s < 8; ++s) {
    v4f lo = *(const v4f*)(xr + s * 16);
    v4f h4 = *(const v4f*)(xr + s * 16 + 4);
    v4u w;
    w[0] = cvt_pk_bf16(lo[0], lo[1]);
    w[1] = cvt_pk_bf16(lo[2], lo[3]);
    w[2] = cvt_pk_bf16(h4[0], h4[1]);
    w[3] = cvt_pk_bf16(h4[2], h4[3]);
    xb[s] = __builtin_bit_cast(v8s, w);
    #pragma unroll
    for (int j = 0; j < 4; ++j) {
      a2 = fmaf(lo[j], lo[j], a2);
      a2 = fmaf(h4[j], h4[j], a2);
    }
  }
  a2 += __shfl_xor(a2, 32);                    // ||x_row||^2, row = l31

  // ---- dist: this wave's 4 ct (c in [h*128, h*128+128)) ----
  float s1 = 0.f, su = 0.f;
  const ushort_t* pb = PbfA + lane * 8;
  const ushort_t* gb = GbfA + lane * 8;
  #pragma unroll
  for (int ct8 = 0; ct8 < 4; ++ct8) {
    const int ct = h * 4 + ct8;
    f32x16 aP, aG;
    #pragma unroll
    for (int i = 0; i < 16; ++i) { aP[i] = 0.f; aG[i] = 0.f; }
    #pragma unroll
    for (int s = 0; s < 8; ++s) {
      v8s ap = *(const v8s*)(pb + (ct * 8 + s) * 512);
      v8s ag = *(const v8s*)(gb + (ct * 8 + s) * 512);
      aP = __builtin_amdgcn_mfma_f32_32x32x16_bf16(ap, xb[s], aP, 0, 0, 0);
      aG = __builtin_amdgcn_mfma_f32_32x32x16_bf16(ag, xb[s], aG, 0, 0, 0);
    }
    #pragma unroll
    for (int q = 0; q < 4; ++q) {
      int c0 = ct * 32 + q * 8 + hi * 4;
      v4f bp = *(const v4f*)(b2p + c0);
      v4f bg = *(const v4f*)(b2g + c0);
      v4f gt = *(const v4f*)(gatev + c0);
      float uf[4];
      #pragma unroll
      for (int j2 = 0; j2 < 4; ++j2) {
        int r = q * 4 + j2;
        float d2a = fmaf(-2.f, aP[r], a2 + bp[j2]);
        float d2b = fmaf(-2.f, aG[r], a2 + bg[j2]);
        float d = __builtin_amdgcn_sqrtf(fmaxf(d2a, 1e-12f))
                + __builtin_amdgcn_sqrtf(fmaxf(d2b, 1e-12f));
        float e = __builtin_amdgcn_exp2f(-d * k2);
        float uu = e * gt[j2];
        s1 += e; su += uu;
        uf[j2] = uu;
      }
      v2u pk;
      pk[0] = cvt_pk_bf16(uf[0], uf[1]);
      pk[1] = cvt_pk_bf16(uf[2], uf[3]);
      *(v2u*)(wl + l31 * 512 + ((ct * 64 + q * 16 + hi * 8) ^ rsw)) = pk;
    }
  }
  s1 += __shfl_xor(s1, 32);
  su += __shfl_xor(su, 32);
  if (hi == 0) {
    sums[h * 64 + l31]      = s1;
    sums[h * 64 + 32 + l31] = su;
  }
  __syncthreads();                              // u + sums complete for the pair

  float s1t = sums[l31] + sums[64 + l31];
  float sut = sums[32 + l31] + sums[96 + l31];
  float scale = 1.f / (sut + 1e-8f * (s1t + 1e-8f));   // exact algebra of double norm

  // ---- w emit: this wave's 16 rows, full-128B-line stores ----
  #pragma unroll
  for (int pp = 0; pp < 2; ++pp) {
    int row = (lane >> 3) + 8 * (2 * h + pp);
    float rsc = __shfl(scale, row);
    float* wdst = w_out + (size_t)(R + row) * NC + (lane & 7) * 4;
    #pragma unroll
    for (int ch = 0; ch < 8; ++ch) {
      v2u pk = *(const v2u*)(wl + row * 512 + ((ch * 64 + (lane & 7) * 8) ^ ((row & 7) << 4)));
      v4f wv;
      wv[0] = bf_lo(pk[0]) * rsc;
      wv[1] = bf_hi(pk[0]) * rsc;
      wv[2] = bf_lo(pk[1]) * rsc;
      wv[3] = bf_hi(pk[1]) * rsc;
      *(v4f*)(wdst + ch * 32) = wv;
    }
  }

  // ---- blend: this wave's 2 dt (d in [h*64, h*64+64)), B-frags from shared u ----
  f32x16 acc[2];
  #pragma unroll
  for (int dt2 = 0; dt2 < 2; ++dt2)
    #pragma unroll
    for (int i = 0; i < 16; ++i) acc[dt2][i] = 0.f;

  const ushort_t* tb = PTbfA + lane * 8;
  #pragma unroll
  for (int s2 = 0; s2 < 16; ++s2) {
    v4u bw = *(const v4u*)(wl + l31 * 512 + ((s2 * 32 + hi * 16) ^ rsw));
    v8s bfrag = __builtin_bit_cast(v8s, bw);
    #pragma unroll
    for (int dt2 = 0; dt2 < 2; ++dt2) {
      int dtg = h * 2 + dt2;
      v8s pa = *(const v8s*)(tb + (dtg * 16 + s2) * 512);
      acc[dt2] = __builtin_amdgcn_mfma_f32_32x32x16_bf16(pa, bfrag, acc[dt2], 0, 0, 0);
    }
  }
  __syncthreads();                              // all u reads done; tile reusable

  // ---- stage this wave's d-half (f32) into the pair tile ----
  #pragma unroll
  for (int dt2 = 0; dt2 < 2; ++dt2) {
    int dtg = h * 2 + dt2;
    #pragma unroll
    for (int q = 0; q < 4; ++q) {
      v4f ov;
      ov[0] = acc[dt2][4 * q + 0] * scale;
      ov[1] = acc[dt2][4 * q + 1] * scale;
      ov[2] = acc[dt2][4 * q + 2] * scale;
      ov[3] = acc[dt2][4 * q + 3] * scale;
      *(v4f*)(wl + l31 * 512 + ((dtg * 128 + q * 32 + hi * 16) ^ rsw)) = ov;
    }
  }
  __syncthreads();                              // full [32m][128d] staged

  // ---- blended emit: this wave's 16 rows, full lines ----
  #pragma unroll
  for (int pp = 0; pp < 2; ++pp) {
    int row = (lane >> 3) + 8 * (2 * h + pp);
    float* bdst = blended_out + (size_t)(R + row) * ND + (lane & 7) * 4;
    #pragma unroll
    for (int ch = 0; ch < 4; ++ch) {
      v4f bv = *(const v4f*)(wl + row * 512 + ((ch * 128 + (lane & 7) * 16) ^ ((row & 7) << 4)));
      *(v4f*)(bdst + ch * 32) = bv;
    }
  }
}

extern "C" void kernel_launch(void* const* d_in, const int* in_sizes, int n_in,
                              void* d_out, int out_size, void* d_ws, size_t ws_size,
                              hipStream_t stream) {
  const float* x    = (const float*)d_in[0];
  const float* P    = (const float*)d_in[1];
  const float* G    = (const float*)d_in[2];
  const float* traw = (const float*)d_in[3];
  const float* gl   = (const float*)d_in[4];
  const int N = in_sizes[0] / ND;             // 262144

  char* ws = (char*)d_ws;
  ushort_t* PbfA  = (ushort_t*)(ws);
  ushort_t* GbfA  = (ushort_t*)(ws + 65536);
  ushort_t* PTbfA = (ushort_t*)(ws + 131072);
  float* b2p   = (float*)(ws + 196608);
  float* b2g   = (float*)(ws + 197632);
  float* gatev = (float*)(ws + 198656);

  float* blended = (float*)d_out;
  float* wout    = blended + (size_t)N * ND;

  som_prep_kernel<<<NC, ND, 0, stream>>>(P, G, gl, PbfA, GbfA, PTbfA, b2p, b2g, gatev);
  som_main_kernel<<<N / 128, 512, 0, stream>>>(x, PbfA, GbfA, PTbfA, b2p, b2g, gatev,
                                               traw, blended, wout);
}